// Round 1
// baseline (89.162 us; speedup 1.0000x reference)
//
#include <hip/hip_runtime.h>

#define NV 50000
#define NJ 24
#define NBETA 10
#define NP 207          // (24-1)*9
#define NROWS 150000    // NV*3

// K1 grid
#define K1_BLOCKS 98    // 98 blocks * 2 tiles * 256 = 50176 >= 50000

// ws layout (float offsets)
#define PARTIAL_OFF 0               // 98*72 = 7056 floats
#define LROT_OFF    8192            // 207 floats
#define M_OFF       8448            // 24*12 = 288 floats

__device__ const int d_par[NJ] = {0,0,0,0,1,2,3,4,5,6,7,8,9,9,9,12,13,14,16,17,18,19,20,21};
__device__ const int d_lvl[NJ] = {0,1,1,1,2,2,2,3,3,3,4,4,4,4,4,5,5,5,6,6,7,7,8,8};

// ---------------------------------------------------------------------------
// K1: per-block partial J = J_regressor @ v_shaped
// ---------------------------------------------------------------------------
__global__ __launch_bounds__(256) void k1_partialJ(
    const float* __restrict__ betas, const float* __restrict__ shapedirs,
    const float* __restrict__ v_template, const float* __restrict__ Jreg,
    float* __restrict__ ws)
{
    __shared__ float sd[256 * 30];
    __shared__ float vt[256 * 3];
    __shared__ float bet[NBETA];
    __shared__ float red[4 * 72];

    const int t = threadIdx.x;
    const int blk = blockIdx.x;
    if (t < NBETA) bet[t] = betas[t];

    float accJ[72];
#pragma unroll
    for (int q = 0; q < 72; q++) accJ[q] = 0.f;

    for (int k = 0; k < 2; k++) {
        const int tile  = k * K1_BLOCKS + blk;
        const int vbase = tile * 256;
        const int nv    = min(256, NV - vbase);   // 256 or 80; never <=0 here
        __syncthreads();   // protect LDS reuse across k iterations
        {
            const int nf = nv * 30;               // divisible by 4 for nv in {256,80}
            const float4* sdg = (const float4*)(shapedirs + (size_t)vbase * 30);
            const int nf4 = nf >> 2;
            for (int i = t; i < nf4; i += 256) ((float4*)sd)[i] = sdg[i];
            const float* vtg = v_template + (size_t)vbase * 3;
            const int nf3 = nv * 3;
            for (int i = t; i < nf3; i += 256) vt[i] = vtg[i];
        }
        __syncthreads();
        const int v = vbase + t;
        if (v < NV) {
            float vs0 = vt[t * 3 + 0], vs1 = vt[t * 3 + 1], vs2 = vt[t * 3 + 2];
#pragma unroll
            for (int i = 0; i < NBETA; i++) {
                const float b = bet[i];
                vs0 += sd[t * 30 + 0 * 10 + i] * b;
                vs1 += sd[t * 30 + 1 * 10 + i] * b;
                vs2 += sd[t * 30 + 2 * 10 + i] * b;
            }
#pragma unroll
            for (int j = 0; j < NJ; j++) {
                const float w = Jreg[(size_t)j * NV + v];
                accJ[j * 3 + 0] += w * vs0;
                accJ[j * 3 + 1] += w * vs1;
                accJ[j * 3 + 2] += w * vs2;
            }
        }
    }

    const int lane = t & 63, wv = t >> 6;
#pragma unroll
    for (int q = 0; q < 72; q++) {
        float x = accJ[q];
#pragma unroll
        for (int m = 1; m < 64; m <<= 1) x += __shfl_xor(x, m);
        if (lane == 0) red[wv * 72 + q] = x;
    }
    __syncthreads();
    if (t < 72)
        ws[PARTIAL_OFF + blk * 72 + t] = red[t] + red[72 + t] + red[144 + t] + red[216 + t];
}

// ---------------------------------------------------------------------------
// K2: reduce partials -> J; rodrigues; kinematic chain; write lrotmin + M
// ---------------------------------------------------------------------------
__global__ __launch_bounds__(256) void k2_small(
    const float* __restrict__ pose, float* __restrict__ ws)
{
    __shared__ float Jl[NJ * 3];
    __shared__ float Rl[NJ * 9];
    __shared__ float Gl[NJ * 12];
    const int t = threadIdx.x;

    if (t < 72) {
        float s = 0.f;
        for (int b = 0; b < K1_BLOCKS; b++) s += ws[PARTIAL_OFF + b * 72 + t];
        Jl[t] = s;
    }
    __syncthreads();

    if (t < NJ) {
        const float x = pose[t * 3 + 0], y = pose[t * 3 + 1], z = pose[t * 3 + 2];
        const float ex = x + 1e-8f, ey = y + 1e-8f, ez = z + 1e-8f;
        const float theta = sqrtf(ex * ex + ey * ey + ez * ez);
        const float inv = 1.f / theta;
        const float rx = x * inv, ry = y * inv, rz = z * inv;
        const float c = cosf(theta), s = sinf(theta), omc = 1.f - c;
        float R[9];
        R[0] = c + omc * rx * rx;      R[1] = omc * rx * ry - s * rz; R[2] = omc * rx * rz + s * ry;
        R[3] = omc * ry * rx + s * rz; R[4] = c + omc * ry * ry;      R[5] = omc * ry * rz - s * rx;
        R[6] = omc * rz * rx - s * ry; R[7] = omc * rz * ry + s * rx; R[8] = c + omc * rz * rz;
#pragma unroll
        for (int q = 0; q < 9; q++) Rl[t * 9 + q] = R[q];
        if (t >= 1) {
#pragma unroll
            for (int q = 0; q < 9; q++)
                ws[LROT_OFF + (t - 1) * 9 + q] = R[q] - ((q == 0 || q == 4 || q == 8) ? 1.f : 0.f);
        }
    }
    __syncthreads();

    for (int L = 0; L < 9; L++) {
        if (t < NJ && d_lvl[t] == L) {
            if (t == 0) {
#pragma unroll
                for (int r = 0; r < 3; r++) {
                    Gl[r * 4 + 0] = Rl[r * 3 + 0];
                    Gl[r * 4 + 1] = Rl[r * 3 + 1];
                    Gl[r * 4 + 2] = Rl[r * 3 + 2];
                    Gl[r * 4 + 3] = Jl[r];
                }
            } else {
                const int p = d_par[t];
                const float tx = Jl[t * 3 + 0] - Jl[p * 3 + 0];
                const float ty = Jl[t * 3 + 1] - Jl[p * 3 + 1];
                const float tz = Jl[t * 3 + 2] - Jl[p * 3 + 2];
#pragma unroll
                for (int r = 0; r < 3; r++) {
                    const float g0 = Gl[p * 12 + r * 4 + 0];
                    const float g1 = Gl[p * 12 + r * 4 + 1];
                    const float g2 = Gl[p * 12 + r * 4 + 2];
                    const float g3 = Gl[p * 12 + r * 4 + 3];
                    Gl[t * 12 + r * 4 + 0] = g0 * Rl[t * 9 + 0] + g1 * Rl[t * 9 + 3] + g2 * Rl[t * 9 + 6];
                    Gl[t * 12 + r * 4 + 1] = g0 * Rl[t * 9 + 1] + g1 * Rl[t * 9 + 4] + g2 * Rl[t * 9 + 7];
                    Gl[t * 12 + r * 4 + 2] = g0 * Rl[t * 9 + 2] + g1 * Rl[t * 9 + 5] + g2 * Rl[t * 9 + 8];
                    Gl[t * 12 + r * 4 + 3] = g0 * tx + g1 * ty + g2 * tz + g3;
                }
            }
        }
        __syncthreads();
    }

    if (t < NJ) {
        const float jx = Jl[t * 3 + 0], jy = Jl[t * 3 + 1], jz = Jl[t * 3 + 2];
#pragma unroll
        for (int r = 0; r < 3; r++) {
            const float g0 = Gl[t * 12 + r * 4 + 0];
            const float g1 = Gl[t * 12 + r * 4 + 1];
            const float g2 = Gl[t * 12 + r * 4 + 2];
            const float g3 = Gl[t * 12 + r * 4 + 3];
            ws[M_OFF + t * 12 + r * 4 + 0] = g0;
            ws[M_OFF + t * 12 + r * 4 + 1] = g1;
            ws[M_OFF + t * 12 + r * 4 + 2] = g2;
            ws[M_OFF + t * 12 + r * 4 + 3] = g3 - (g0 * jx + g1 * jy + g2 * jz);
        }
    }
}

// ---------------------------------------------------------------------------
// K3: v_posed (pose-GEMV, wave-per-row) + skinning, 64 vertices / block
// ---------------------------------------------------------------------------
__global__ __launch_bounds__(256) void k3_vertices(
    const float* __restrict__ betas, const float* __restrict__ trans,
    const float* __restrict__ shapedirs, const float* __restrict__ v_template,
    const float* __restrict__ weights, const float* __restrict__ posedirs,
    const float* __restrict__ ws, float* __restrict__ out)
{
    __shared__ float vposed[192];
    __shared__ float vt[192];
    __shared__ float Ml[288];

    const int t = threadIdx.x;
    const int lane = t & 63, wv = t >> 6;
    const int blk = blockIdx.x;
    const int rbase = blk * 192;

    if (t < 192) {
        const int gr = rbase + t;
        vt[t] = (gr < NROWS) ? v_template[gr] : 0.f;
    }
    Ml[t] = ws[M_OFF + t];
    if (t < 32) Ml[256 + t] = ws[M_OFF + 256 + t];

    const float lr0 = ws[LROT_OFF + lane];
    const float lr1 = ws[LROT_OFF + 64 + lane];
    const float lr2 = ws[LROT_OFF + 128 + lane];
    const float lr3 = (lane < 15) ? ws[LROT_OFF + 192 + lane] : 0.f;
    const float bet = (lane < NBETA) ? betas[lane] : 0.f;
    __syncthreads();

    // phase 1: one row (v,c) per wave-iteration
    for (int i = 0; i < 48; i++) {
        const int rl = wv * 48 + i;
        const int gr = rbase + rl;
        float acc = 0.f;
        if (gr < NROWS) {
            const float* pd = posedirs + (size_t)gr * NP;
            acc = pd[lane] * lr0 + pd[64 + lane] * lr1 + pd[128 + lane] * lr2;
            if (lane < 15) acc += pd[192 + lane] * lr3;
            if (lane < NBETA) acc += shapedirs[(size_t)gr * 10 + lane] * bet;
        }
#pragma unroll
        for (int m = 1; m < 64; m <<= 1) acc += __shfl_xor(acc, m);
        if (lane == 0 && gr < NROWS) vposed[rl] = acc + vt[rl];
    }
    __syncthreads();

    // phase 2: skinning, one vertex per thread (threads 0..63)
    if (t < 64) {
        const int v = blk * 64 + t;
        if (v < NV) {
            float T[12];
#pragma unroll
            for (int q = 0; q < 12; q++) T[q] = 0.f;
            const float* w = weights + (size_t)v * 24;
#pragma unroll
            for (int j = 0; j < NJ; j++) {
                const float wj = w[j];
#pragma unroll
                for (int q = 0; q < 12; q++) T[q] += wj * Ml[j * 12 + q];
            }
            const float p0 = vposed[t * 3 + 0];
            const float p1 = vposed[t * 3 + 1];
            const float p2 = vposed[t * 3 + 2];
            out[(size_t)v * 3 + 0] = T[0] * p0 + T[1] * p1 + T[2]  * p2 + T[3]  + trans[0];
            out[(size_t)v * 3 + 1] = T[4] * p0 + T[5] * p1 + T[6]  * p2 + T[7]  + trans[1];
            out[(size_t)v * 3 + 2] = T[8] * p0 + T[9] * p1 + T[10] * p2 + T[11] + trans[2];
        }
    }
}

extern "C" void kernel_launch(void* const* d_in, const int* in_sizes, int n_in,
                              void* d_out, int out_size, void* d_ws, size_t ws_size,
                              hipStream_t stream) {
    const float* betas      = (const float*)d_in[0];
    const float* pose       = (const float*)d_in[1];
    const float* trans      = (const float*)d_in[2];
    const float* shapedirs  = (const float*)d_in[3];
    const float* v_template = (const float*)d_in[4];
    const float* Jreg       = (const float*)d_in[5];
    const float* weights    = (const float*)d_in[6];
    const float* posedirs   = (const float*)d_in[7];
    float* ws  = (float*)d_ws;
    float* out = (float*)d_out;

    k1_partialJ<<<dim3(K1_BLOCKS), dim3(256), 0, stream>>>(betas, shapedirs, v_template, Jreg, ws);
    k2_small<<<dim3(1), dim3(256), 0, stream>>>(pose, ws);
    k3_vertices<<<dim3((NV + 63) / 64), dim3(256), 0, stream>>>(
        betas, trans, shapedirs, v_template, weights, posedirs, ws, out);
}

// Round 2
// 57.032 us; speedup vs baseline: 1.5634x; 1.5634x over previous
//
#include <hip/hip_runtime.h>

#define NV 50000
#define NJ 24
#define NBETA 10
#define NP 207          // (24-1)*9
#define NROWS 150000    // NV*3
#define ROWGROUPS 37500 // NROWS/4

// K1 grid
#define K1_BLOCKS 196   // 196 * 256 = 50176 >= 50000

// ws layout (float offsets)
#define PARTIAL_OFF 0        // 196*72 = 14112 floats
#define LROT_OFF    14336    // 207 floats
#define M_OFF       14592    // 24*12 = 288 floats

__device__ const int d_par[NJ] = {0,0,0,0,1,2,3,4,5,6,7,8,9,9,9,12,13,14,16,17,18,19,20,21};
__device__ const int d_lvl[NJ] = {0,1,1,1,2,2,2,3,3,3,4,4,4,4,4,5,5,5,6,6,7,7,8,8};

// ---------------------------------------------------------------------------
// K1: per-block partial J = J_regressor @ v_shaped  (one 256-vertex tile/block)
// ---------------------------------------------------------------------------
__global__ __launch_bounds__(256) void k1_partialJ(
    const float* __restrict__ betas, const float* __restrict__ shapedirs,
    const float* __restrict__ v_template, const float* __restrict__ Jreg,
    float* __restrict__ ws)
{
    __shared__ float sd[256 * 30];
    __shared__ float vt[256 * 3];
    __shared__ float bet[NBETA];
    __shared__ float red[4 * 72];

    const int t = threadIdx.x;
    const int blk = blockIdx.x;
    if (t < NBETA) bet[t] = betas[t];

    const int vbase = blk * 256;
    const int nv    = min(256, NV - vbase);   // 256, or 80 for last block
    {
        const int nf4 = (nv * 30) >> 2;       // divisible by 4 for nv in {256,80}
        const float4* sdg = (const float4*)(shapedirs + (size_t)vbase * 30);
        for (int i = t; i < nf4; i += 256) ((float4*)sd)[i] = sdg[i];
        const float* vtg = v_template + (size_t)vbase * 3;
        const int nf3 = nv * 3;
        for (int i = t; i < nf3; i += 256) vt[i] = vtg[i];
    }
    __syncthreads();

    float accJ[72];
#pragma unroll
    for (int q = 0; q < 72; q++) accJ[q] = 0.f;

    const int v = vbase + t;
    if (v < NV) {
        float vs0 = vt[t * 3 + 0], vs1 = vt[t * 3 + 1], vs2 = vt[t * 3 + 2];
#pragma unroll
        for (int i = 0; i < NBETA; i++) {
            const float b = bet[i];
            vs0 += sd[t * 30 + 0 * 10 + i] * b;
            vs1 += sd[t * 30 + 1 * 10 + i] * b;
            vs2 += sd[t * 30 + 2 * 10 + i] * b;
        }
#pragma unroll
        for (int j = 0; j < NJ; j++) {
            const float w = Jreg[(size_t)j * NV + v];
            accJ[j * 3 + 0] += w * vs0;
            accJ[j * 3 + 1] += w * vs1;
            accJ[j * 3 + 2] += w * vs2;
        }
    }

    const int lane = t & 63, wv = t >> 6;
#pragma unroll
    for (int q = 0; q < 72; q++) {
        float x = accJ[q];
#pragma unroll
        for (int m = 1; m < 64; m <<= 1) x += __shfl_xor(x, m);
        if (lane == 0) red[wv * 72 + q] = x;
    }
    __syncthreads();
    if (t < 72)
        ws[PARTIAL_OFF + blk * 72 + t] = red[t] + red[72 + t] + red[144 + t] + red[216 + t];
}

// ---------------------------------------------------------------------------
// K2: reduce partials -> J; rodrigues; kinematic chain; write lrotmin + M
// ---------------------------------------------------------------------------
__global__ __launch_bounds__(256) void k2_small(
    const float* __restrict__ pose, float* __restrict__ ws)
{
    __shared__ float Jl[NJ * 3];
    __shared__ float Rl[NJ * 9];
    __shared__ float Gl[NJ * 12];
    const int t = threadIdx.x;

    if (t < 72) {
        float s0 = 0.f, s1 = 0.f;
        for (int b = 0; b < K1_BLOCKS; b += 2) {
            s0 += ws[PARTIAL_OFF + b * 72 + t];
            s1 += ws[PARTIAL_OFF + (b + 1) * 72 + t];
        }
        Jl[t] = s0 + s1;
    }
    __syncthreads();

    if (t < NJ) {
        const float x = pose[t * 3 + 0], y = pose[t * 3 + 1], z = pose[t * 3 + 2];
        const float ex = x + 1e-8f, ey = y + 1e-8f, ez = z + 1e-8f;
        const float theta = sqrtf(ex * ex + ey * ey + ez * ez);
        const float inv = 1.f / theta;
        const float rx = x * inv, ry = y * inv, rz = z * inv;
        const float c = cosf(theta), s = sinf(theta), omc = 1.f - c;
        float R[9];
        R[0] = c + omc * rx * rx;      R[1] = omc * rx * ry - s * rz; R[2] = omc * rx * rz + s * ry;
        R[3] = omc * ry * rx + s * rz; R[4] = c + omc * ry * ry;      R[5] = omc * ry * rz - s * rx;
        R[6] = omc * rz * rx - s * ry; R[7] = omc * rz * ry + s * rx; R[8] = c + omc * rz * rz;
#pragma unroll
        for (int q = 0; q < 9; q++) Rl[t * 9 + q] = R[q];
        if (t >= 1) {
#pragma unroll
            for (int q = 0; q < 9; q++)
                ws[LROT_OFF + (t - 1) * 9 + q] = R[q] - ((q == 0 || q == 4 || q == 8) ? 1.f : 0.f);
        }
    }
    __syncthreads();

    for (int L = 0; L < 9; L++) {
        if (t < NJ && d_lvl[t] == L) {
            if (t == 0) {
#pragma unroll
                for (int r = 0; r < 3; r++) {
                    Gl[r * 4 + 0] = Rl[r * 3 + 0];
                    Gl[r * 4 + 1] = Rl[r * 3 + 1];
                    Gl[r * 4 + 2] = Rl[r * 3 + 2];
                    Gl[r * 4 + 3] = Jl[r];
                }
            } else {
                const int p = d_par[t];
                const float tx = Jl[t * 3 + 0] - Jl[p * 3 + 0];
                const float ty = Jl[t * 3 + 1] - Jl[p * 3 + 1];
                const float tz = Jl[t * 3 + 2] - Jl[p * 3 + 2];
#pragma unroll
                for (int r = 0; r < 3; r++) {
                    const float g0 = Gl[p * 12 + r * 4 + 0];
                    const float g1 = Gl[p * 12 + r * 4 + 1];
                    const float g2 = Gl[p * 12 + r * 4 + 2];
                    const float g3 = Gl[p * 12 + r * 4 + 3];
                    Gl[t * 12 + r * 4 + 0] = g0 * Rl[t * 9 + 0] + g1 * Rl[t * 9 + 3] + g2 * Rl[t * 9 + 6];
                    Gl[t * 12 + r * 4 + 1] = g0 * Rl[t * 9 + 1] + g1 * Rl[t * 9 + 4] + g2 * Rl[t * 9 + 7];
                    Gl[t * 12 + r * 4 + 2] = g0 * Rl[t * 9 + 2] + g1 * Rl[t * 9 + 5] + g2 * Rl[t * 9 + 8];
                    Gl[t * 12 + r * 4 + 3] = g0 * tx + g1 * ty + g2 * tz + g3;
                }
            }
        }
        __syncthreads();
    }

    if (t < NJ) {
        const float jx = Jl[t * 3 + 0], jy = Jl[t * 3 + 1], jz = Jl[t * 3 + 2];
#pragma unroll
        for (int r = 0; r < 3; r++) {
            const float g0 = Gl[t * 12 + r * 4 + 0];
            const float g1 = Gl[t * 12 + r * 4 + 1];
            const float g2 = Gl[t * 12 + r * 4 + 2];
            const float g3 = Gl[t * 12 + r * 4 + 3];
            ws[M_OFF + t * 12 + r * 4 + 0] = g0;
            ws[M_OFF + t * 12 + r * 4 + 1] = g1;
            ws[M_OFF + t * 12 + r * 4 + 2] = g2;
            ws[M_OFF + t * 12 + r * 4 + 3] = g3 - (g0 * jx + g1 * jy + g2 * jz);
        }
    }
}

// ---------------------------------------------------------------------------
// K3a: v_posed GEMV. 16 lanes per row, 4 rows per wave per iteration,
//      one 4-step butterfly reduces all 4 rows at once. Writes vposed -> out.
// ---------------------------------------------------------------------------
__global__ __launch_bounds__(256) void k3a_posegemv(
    const float* __restrict__ betas, const float* __restrict__ shapedirs,
    const float* __restrict__ v_template, const float* __restrict__ posedirs,
    const float* __restrict__ ws, float* __restrict__ out)
{
    const int t = threadIdx.x;
    const int lane = t & 63, wv = t >> 6;
    const int l16 = lane & 15, g = lane >> 4;

    // lrotmin: lane holds cols {l16, 16+l16, ..., 192+l16}
    float lrk[12];
#pragma unroll
    for (int k = 0; k < 12; k++) lrk[k] = ws[LROT_OFF + k * 16 + l16];
    const float lr12 = (l16 < 15) ? ws[LROT_OFF + 192 + l16] : 0.f;
    const float bet  = (l16 < NBETA) ? betas[l16] : 0.f;

    const int wgid    = blockIdx.x * 4 + wv;
    const int wstride = gridDim.x * 4;

    for (int grp = wgid; grp < ROWGROUPS; grp += wstride) {
        const int row = grp * 4 + g;
        const float* pd = posedirs + (size_t)row * NP;
        float acc = 0.f;
#pragma unroll
        for (int k = 0; k < 12; k++) acc += pd[k * 16 + l16] * lrk[k];
        if (l16 < 15)    acc += pd[192 + l16] * lr12;
        if (l16 < NBETA) acc += shapedirs[(size_t)row * NBETA + l16] * bet;
#pragma unroll
        for (int m = 1; m < 16; m <<= 1) acc += __shfl_xor(acc, m);
        if (l16 == 0) out[row] = acc + v_template[row];
    }
}

// ---------------------------------------------------------------------------
// K3b: skinning, one vertex per thread, in-place on out (vposed -> final v)
// ---------------------------------------------------------------------------
__global__ __launch_bounds__(256) void k3b_skin(
    const float* __restrict__ trans, const float* __restrict__ weights,
    const float* __restrict__ ws, float* __restrict__ out)
{
    __shared__ float Ml[288];
    const int t = threadIdx.x;
    Ml[t] = ws[M_OFF + t];
    if (t < 32) Ml[256 + t] = ws[M_OFF + 256 + t];
    __syncthreads();

    const int v = blockIdx.x * 256 + t;
    if (v >= NV) return;

    const float4* w4 = (const float4*)(weights + (size_t)v * 24);
    float wj[24];
#pragma unroll
    for (int q = 0; q < 6; q++) {
        const float4 w = w4[q];
        wj[q * 4 + 0] = w.x; wj[q * 4 + 1] = w.y;
        wj[q * 4 + 2] = w.z; wj[q * 4 + 3] = w.w;
    }

    float T[12];
#pragma unroll
    for (int q = 0; q < 12; q++) T[q] = 0.f;
#pragma unroll
    for (int j = 0; j < NJ; j++) {
        const float w = wj[j];
#pragma unroll
        for (int q = 0; q < 12; q++) T[q] += w * Ml[j * 12 + q];
    }

    const float p0 = out[(size_t)v * 3 + 0];
    const float p1 = out[(size_t)v * 3 + 1];
    const float p2 = out[(size_t)v * 3 + 2];
    out[(size_t)v * 3 + 0] = T[0] * p0 + T[1] * p1 + T[2]  * p2 + T[3]  + trans[0];
    out[(size_t)v * 3 + 1] = T[4] * p0 + T[5] * p1 + T[6]  * p2 + T[7]  + trans[1];
    out[(size_t)v * 3 + 2] = T[8] * p0 + T[9] * p1 + T[10] * p2 + T[11] + trans[2];
}

extern "C" void kernel_launch(void* const* d_in, const int* in_sizes, int n_in,
                              void* d_out, int out_size, void* d_ws, size_t ws_size,
                              hipStream_t stream) {
    const float* betas      = (const float*)d_in[0];
    const float* pose       = (const float*)d_in[1];
    const float* trans      = (const float*)d_in[2];
    const float* shapedirs  = (const float*)d_in[3];
    const float* v_template = (const float*)d_in[4];
    const float* Jreg       = (const float*)d_in[5];
    const float* weights    = (const float*)d_in[6];
    const float* posedirs   = (const float*)d_in[7];
    float* ws  = (float*)d_ws;
    float* out = (float*)d_out;

    k1_partialJ<<<dim3(K1_BLOCKS), dim3(256), 0, stream>>>(betas, shapedirs, v_template, Jreg, ws);
    k2_small<<<dim3(1), dim3(256), 0, stream>>>(pose, ws);
    k3a_posegemv<<<dim3(2048), dim3(256), 0, stream>>>(betas, shapedirs, v_template, posedirs, ws, out);
    k3b_skin<<<dim3((NV + 255) / 256), dim3(256), 0, stream>>>(trans, weights, ws, out);
}

// Round 3
// 55.687 us; speedup vs baseline: 1.6011x; 1.0242x over previous
//
#include <hip/hip_runtime.h>

#define NV 50000
#define NJ 24
#define NBETA 10
#define NP 207          // (24-1)*9
#define NROWS 150000    // NV*3

// K1 grid
#define K1_BLOCKS 196   // 196 * 256 = 50176 >= 50000

// K3 fused: 32 vertices / block = 96 rows = 24 groups of 4 rows
#define VPB 32
#define RPB 96
#define GPB 24
#define K3_BLOCKS 1563  // ceil(50000/32)

// ws layout (float offsets)
#define PARTIAL_OFF 0        // 196*72 = 14112 floats
#define LROT_OFF    14336    // 207 floats
#define M_OFF       14592    // 24*12 = 288 floats

__device__ const int d_par[NJ] = {0,0,0,0,1,2,3,4,5,6,7,8,9,9,9,12,13,14,16,17,18,19,20,21};
__device__ const int d_lvl[NJ] = {0,1,1,1,2,2,2,3,3,3,4,4,4,4,4,5,5,5,6,6,7,7,8,8};

// ---------------------------------------------------------------------------
// K1: per-block partial J = J_regressor @ v_shaped  (one 256-vertex tile/block)
// ---------------------------------------------------------------------------
__global__ __launch_bounds__(256) void k1_partialJ(
    const float* __restrict__ betas, const float* __restrict__ shapedirs,
    const float* __restrict__ v_template, const float* __restrict__ Jreg,
    float* __restrict__ ws)
{
    __shared__ float sd[256 * 30];
    __shared__ float vt[256 * 3];
    __shared__ float bet[NBETA];
    __shared__ float red[4 * 72];

    const int t = threadIdx.x;
    const int blk = blockIdx.x;
    if (t < NBETA) bet[t] = betas[t];

    const int vbase = blk * 256;
    const int nv    = min(256, NV - vbase);   // 256, or 80 for last block
    {
        const int nf4 = (nv * 30) >> 2;       // divisible by 4 for nv in {256,80}
        const float4* sdg = (const float4*)(shapedirs + (size_t)vbase * 30);
        for (int i = t; i < nf4; i += 256) ((float4*)sd)[i] = sdg[i];
        const float* vtg = v_template + (size_t)vbase * 3;
        const int nf3 = nv * 3;
        for (int i = t; i < nf3; i += 256) vt[i] = vtg[i];
    }
    __syncthreads();

    float accJ[72];
#pragma unroll
    for (int q = 0; q < 72; q++) accJ[q] = 0.f;

    const int v = vbase + t;
    if (v < NV) {
        float vs0 = vt[t * 3 + 0], vs1 = vt[t * 3 + 1], vs2 = vt[t * 3 + 2];
#pragma unroll
        for (int i = 0; i < NBETA; i++) {
            const float b = bet[i];
            vs0 += sd[t * 30 + 0 * 10 + i] * b;
            vs1 += sd[t * 30 + 1 * 10 + i] * b;
            vs2 += sd[t * 30 + 2 * 10 + i] * b;
        }
#pragma unroll
        for (int j = 0; j < NJ; j++) {
            const float w = Jreg[(size_t)j * NV + v];
            accJ[j * 3 + 0] += w * vs0;
            accJ[j * 3 + 1] += w * vs1;
            accJ[j * 3 + 2] += w * vs2;
        }
    }

    const int lane = t & 63, wv = t >> 6;
#pragma unroll
    for (int q = 0; q < 72; q++) {
        float x = accJ[q];
#pragma unroll
        for (int m = 1; m < 64; m <<= 1) x += __shfl_xor(x, m);
        if (lane == 0) red[wv * 72 + q] = x;
    }
    __syncthreads();
    if (t < 72)
        ws[PARTIAL_OFF + blk * 72 + t] = red[t] + red[72 + t] + red[144 + t] + red[216 + t];
}

// ---------------------------------------------------------------------------
// K2: reduce partials -> J; rodrigues; kinematic chain; write lrotmin + M
// ---------------------------------------------------------------------------
__global__ __launch_bounds__(256) void k2_small(
    const float* __restrict__ pose, float* __restrict__ ws)
{
    __shared__ float Jl[NJ * 3];
    __shared__ float Rl[NJ * 9];
    __shared__ float Gl[NJ * 12];
    const int t = threadIdx.x;

    if (t < 72) {
        float s0 = 0.f, s1 = 0.f;
        for (int b = 0; b < K1_BLOCKS; b += 2) {
            s0 += ws[PARTIAL_OFF + b * 72 + t];
            s1 += ws[PARTIAL_OFF + (b + 1) * 72 + t];
        }
        Jl[t] = s0 + s1;
    }
    __syncthreads();

    if (t < NJ) {
        const float x = pose[t * 3 + 0], y = pose[t * 3 + 1], z = pose[t * 3 + 2];
        const float ex = x + 1e-8f, ey = y + 1e-8f, ez = z + 1e-8f;
        const float theta = sqrtf(ex * ex + ey * ey + ez * ez);
        const float inv = 1.f / theta;
        const float rx = x * inv, ry = y * inv, rz = z * inv;
        const float c = cosf(theta), s = sinf(theta), omc = 1.f - c;
        float R[9];
        R[0] = c + omc * rx * rx;      R[1] = omc * rx * ry - s * rz; R[2] = omc * rx * rz + s * ry;
        R[3] = omc * ry * rx + s * rz; R[4] = c + omc * ry * ry;      R[5] = omc * ry * rz - s * rx;
        R[6] = omc * rz * rx - s * ry; R[7] = omc * rz * ry + s * rx; R[8] = c + omc * rz * rz;
#pragma unroll
        for (int q = 0; q < 9; q++) Rl[t * 9 + q] = R[q];
        if (t >= 1) {
#pragma unroll
            for (int q = 0; q < 9; q++)
                ws[LROT_OFF + (t - 1) * 9 + q] = R[q] - ((q == 0 || q == 4 || q == 8) ? 1.f : 0.f);
        }
    }
    __syncthreads();

    for (int L = 0; L < 9; L++) {
        if (t < NJ && d_lvl[t] == L) {
            if (t == 0) {
#pragma unroll
                for (int r = 0; r < 3; r++) {
                    Gl[r * 4 + 0] = Rl[r * 3 + 0];
                    Gl[r * 4 + 1] = Rl[r * 3 + 1];
                    Gl[r * 4 + 2] = Rl[r * 3 + 2];
                    Gl[r * 4 + 3] = Jl[r];
                }
            } else {
                const int p = d_par[t];
                const float tx = Jl[t * 3 + 0] - Jl[p * 3 + 0];
                const float ty = Jl[t * 3 + 1] - Jl[p * 3 + 1];
                const float tz = Jl[t * 3 + 2] - Jl[p * 3 + 2];
#pragma unroll
                for (int r = 0; r < 3; r++) {
                    const float g0 = Gl[p * 12 + r * 4 + 0];
                    const float g1 = Gl[p * 12 + r * 4 + 1];
                    const float g2 = Gl[p * 12 + r * 4 + 2];
                    const float g3 = Gl[p * 12 + r * 4 + 3];
                    Gl[t * 12 + r * 4 + 0] = g0 * Rl[t * 9 + 0] + g1 * Rl[t * 9 + 3] + g2 * Rl[t * 9 + 6];
                    Gl[t * 12 + r * 4 + 1] = g0 * Rl[t * 9 + 1] + g1 * Rl[t * 9 + 4] + g2 * Rl[t * 9 + 7];
                    Gl[t * 12 + r * 4 + 2] = g0 * Rl[t * 9 + 2] + g1 * Rl[t * 9 + 5] + g2 * Rl[t * 9 + 8];
                    Gl[t * 12 + r * 4 + 3] = g0 * tx + g1 * ty + g2 * tz + g3;
                }
            }
        }
        __syncthreads();
    }

    if (t < NJ) {
        const float jx = Jl[t * 3 + 0], jy = Jl[t * 3 + 1], jz = Jl[t * 3 + 2];
#pragma unroll
        for (int r = 0; r < 3; r++) {
            const float g0 = Gl[t * 12 + r * 4 + 0];
            const float g1 = Gl[t * 12 + r * 4 + 1];
            const float g2 = Gl[t * 12 + r * 4 + 2];
            const float g3 = Gl[t * 12 + r * 4 + 3];
            ws[M_OFF + t * 12 + r * 4 + 0] = g0;
            ws[M_OFF + t * 12 + r * 4 + 1] = g1;
            ws[M_OFF + t * 12 + r * 4 + 2] = g2;
            ws[M_OFF + t * 12 + r * 4 + 3] = g3 - (g0 * jx + g1 * jy + g2 * jz);
        }
    }
}

// ---------------------------------------------------------------------------
// K3 fused: pose-GEMV (16 lanes/row, 4 rows/group, x2 unrolled) + skinning.
// Block owns 32 vertices = 96 rows = 24 groups; wave wv owns groups
// [wv*6, wv*6+6). vposed staged in LDS; skin phase uses threads 0..31.
// ---------------------------------------------------------------------------
__global__ __launch_bounds__(256) void k3_fused(
    const float* __restrict__ betas, const float* __restrict__ trans,
    const float* __restrict__ shapedirs, const float* __restrict__ v_template,
    const float* __restrict__ weights, const float* __restrict__ posedirs,
    const float* __restrict__ ws, float* __restrict__ out)
{
    __shared__ float vposed[RPB];
    __shared__ float Ml[288];

    const int t = threadIdx.x;
    const int lane = t & 63, wv = t >> 6;
    const int l16 = lane & 15, g = lane >> 4;
    const int blk = blockIdx.x;

    Ml[t] = ws[M_OFF + t];
    if (t < 32) Ml[256 + t] = ws[M_OFF + 256 + t];

    // lrotmin fragments: lane owns cols {l16, 16+l16, ..., 176+l16} + tail
    float lrk[12];
#pragma unroll
    for (int k = 0; k < 12; k++) lrk[k] = ws[LROT_OFF + k * 16 + l16];
    const float lr12 = (l16 < 15) ? ws[LROT_OFF + 192 + l16] : 0.f;
    const float bet  = (l16 < NBETA) ? betas[l16] : 0.f;

    // ---- phase 1: GEMV, 6 groups per wave, unrolled x2 ----
    const int gbase = blk * GPB + wv * 6;
#pragma unroll
    for (int i = 0; i < 6; i += 2) {
        const int rowA = (gbase + i) * 4 + g;
        const int rowB = rowA + 4;
        const bool okA = rowA < NROWS;      // wave-uniform (NROWS % 4 == 0)
        const bool okB = rowB < NROWS;

        float va[12], vb[12];
        float tA = 0.f, tB = 0.f, sA = 0.f, sB = 0.f;
        if (okA) {
            const float* pa = posedirs + (size_t)rowA * NP;
#pragma unroll
            for (int k = 0; k < 12; k++) va[k] = pa[k * 16 + l16];
            if (l16 < 15)    tA = pa[192 + l16];
            if (l16 < NBETA) sA = shapedirs[(size_t)rowA * NBETA + l16];
        } else {
#pragma unroll
            for (int k = 0; k < 12; k++) va[k] = 0.f;
        }
        if (okB) {
            const float* pb = posedirs + (size_t)rowB * NP;
#pragma unroll
            for (int k = 0; k < 12; k++) vb[k] = pb[k * 16 + l16];
            if (l16 < 15)    tB = pb[192 + l16];
            if (l16 < NBETA) sB = shapedirs[(size_t)rowB * NBETA + l16];
        } else {
#pragma unroll
            for (int k = 0; k < 12; k++) vb[k] = 0.f;
        }

        float accA = tA * lr12 + sA * bet;
        float accB = tB * lr12 + sB * bet;
#pragma unroll
        for (int k = 0; k < 12; k++) accA += va[k] * lrk[k];
#pragma unroll
        for (int k = 0; k < 12; k++) accB += vb[k] * lrk[k];
#pragma unroll
        for (int m = 1; m < 16; m <<= 1) {
            accA += __shfl_xor(accA, m);
            accB += __shfl_xor(accB, m);
        }
        if (l16 == 0) {
            if (okA) vposed[rowA - blk * RPB] = accA + v_template[rowA];
            if (okB) vposed[rowB - blk * RPB] = accB + v_template[rowB];
        }
    }
    __syncthreads();

    // ---- phase 2: skinning, threads 0..31, one vertex each ----
    if (t < VPB) {
        const int v = blk * VPB + t;
        if (v < NV) {
            const float4* w4 = (const float4*)(weights + (size_t)v * 24);
            float wj[24];
#pragma unroll
            for (int q = 0; q < 6; q++) {
                const float4 w = w4[q];
                wj[q * 4 + 0] = w.x; wj[q * 4 + 1] = w.y;
                wj[q * 4 + 2] = w.z; wj[q * 4 + 3] = w.w;
            }
            float T[12];
#pragma unroll
            for (int q = 0; q < 12; q++) T[q] = 0.f;
#pragma unroll
            for (int j = 0; j < NJ; j++) {
                const float w = wj[j];
#pragma unroll
                for (int q = 0; q < 12; q++) T[q] += w * Ml[j * 12 + q];
            }
            const float p0 = vposed[t * 3 + 0];
            const float p1 = vposed[t * 3 + 1];
            const float p2 = vposed[t * 3 + 2];
            out[(size_t)v * 3 + 0] = T[0] * p0 + T[1] * p1 + T[2]  * p2 + T[3]  + trans[0];
            out[(size_t)v * 3 + 1] = T[4] * p0 + T[5] * p1 + T[6]  * p2 + T[7]  + trans[1];
            out[(size_t)v * 3 + 2] = T[8] * p0 + T[9] * p1 + T[10] * p2 + T[11] + trans[2];
        }
    }
}

extern "C" void kernel_launch(void* const* d_in, const int* in_sizes, int n_in,
                              void* d_out, int out_size, void* d_ws, size_t ws_size,
                              hipStream_t stream) {
    const float* betas      = (const float*)d_in[0];
    const float* pose       = (const float*)d_in[1];
    const float* trans      = (const float*)d_in[2];
    const float* shapedirs  = (const float*)d_in[3];
    const float* v_template = (const float*)d_in[4];
    const float* Jreg       = (const float*)d_in[5];
    const float* weights    = (const float*)d_in[6];
    const float* posedirs   = (const float*)d_in[7];
    float* ws  = (float*)d_ws;
    float* out = (float*)d_out;

    k1_partialJ<<<dim3(K1_BLOCKS), dim3(256), 0, stream>>>(betas, shapedirs, v_template, Jreg, ws);
    k2_small<<<dim3(1), dim3(256), 0, stream>>>(pose, ws);
    k3_fused<<<dim3(K3_BLOCKS), dim3(256), 0, stream>>>(
        betas, trans, shapedirs, v_template, weights, posedirs, ws, out);
}